// Round 13
// baseline (298.953 us; speedup 1.0000x reference)
//
#include <hip/hip_runtime.h>

// LSTMModel: B=4096, T=512, IN=2, H=12, OUT=2, fp32.
// r13: LAYER-SPLIT WAVES. 4096 L0-waves + 4096 L1-waves = 8192 waves
// = 8 waves/SIMD (2x all prior rounds, same 4 elements/SIMD).
// Block = 512 threads: waves 0-3 = L0 for elements e0..e3, waves 4-7 = L1.
// Interval t: L0-wave does step t, writes h0(t) to parity buf[t&1];
// L1-wave does step t-1, reads buf[(t-1)&1]. One __syncthreads per interval.
// L1 never feeds back to L0 -> one-directional pipeline, natural 1-step lag.
// All-scalar math (pk is half-rate, saves nothing at 1 elem/wave);
// all-scalar LDS (consistent TBAA); mov_dpp quad gathers for f,g,o.

namespace {
constexpr int H = 12;
constexpr int T = 512;
constexpr float LOG2E = 1.4426950408889634f;

__device__ __forceinline__ float exp2_(float x) {
    float r; asm("v_exp_f32 %0, %1" : "=v"(r) : "v"(x)); return r;
}
__device__ __forceinline__ float rcp_(float x) { return __builtin_amdgcn_rcpf(x); }
template <int CTRL>
__device__ __forceinline__ float mdpp(float v) {
    return __int_as_float(__builtin_amdgcn_mov_dpp(
        __float_as_int(v), CTRL, 0xF, 0xF, true));
}
constexpr int BC1 = 0x55;  // quad broadcast lane1 -> f
constexpr int BC2 = 0xAA;  // quad broadcast lane2 -> g
constexpr int BC3 = 0xFF;  // quad broadcast lane3 -> o

__device__ __forceinline__ float tanh_(float c) {
    // tanh(c) = 2/(1+2^(-2*log2e*c)) - 1
    return fmaf(2.0f, rcp_(1.0f + exp2_(-2.0f * LOG2E * c)), -1.0f);
}
} // namespace

__global__ __launch_bounds__(512, 8) void lstm2_fc_kernel(
    const float* __restrict__ x,      // (4096, 512, 2)
    const float* __restrict__ W_ih0,  // (48, 2)
    const float* __restrict__ W_hh0,  // (48, 12)
    const float* __restrict__ b_ih0,  // (48)
    const float* __restrict__ b_hh0,  // (48)
    const float* __restrict__ W_ih1,  // (48, 12)
    const float* __restrict__ W_hh1,  // (48, 12)
    const float* __restrict__ b_ih1,  // (48)
    const float* __restrict__ b_hh1,  // (48)
    const float* __restrict__ fc_W,   // (2, 12)
    const float* __restrict__ fc_b,   // (2)
    float* __restrict__ out)          // (4096, 2)
{
    const int tid  = threadIdx.x;
    const int lane = tid & 63;
    const int wv   = __builtin_amdgcn_readfirstlane(tid >> 6);   // 0..7
    const bool L1w = (wv >= 4);                  // waves 4-7 handle layer 1
    const int ew   = wv & 3;                     // element slot in block
    const int b    = blockIdx.x * 4 + ew;
    const int u    = lane >> 2;                  // unit 0..15 (12 active)
    const int gate = lane & 3;                   // 0:i 1:f 2:g 3:o
    const int uc   = (u < H) ? u : 0;
    const int r    = gate * H + uc;              // weight row

    const float pre  = (gate == 2) ? 2.0f : 1.0f;   // tanh for g via 2*sig(2x)-1
    const float kmul = -LOG2E * pre;                // exp2 prescale, folded in
    const float pa   = 1.0f - pre;

    // per-element LDS: h0 parity bufs [0..15],[16..31]; h1 at [32..47]
    __shared__ float sm[4 * 64];
    float* eb = &sm[ew * 64];
    const bool pub = (gate == 0) && (u < H);     // 12 writer lanes, banks 0-11

    // ---------------- per-wave weights (scalar, prescaled) ----------------
    float w[24];    // L0: [0]=wx0 [1]=wx1 [2..13]=whh0 ; L1: [0..11]=wih1 [12..23]=whh1
    float bias;
    if (!L1w) {
        w[0] = kmul * W_ih0[r * 2 + 0];
        w[1] = kmul * W_ih0[r * 2 + 1];
#pragma unroll
        for (int j = 0; j < H; ++j) w[2 + j] = kmul * W_hh0[r * H + j];
#pragma unroll
        for (int j = 0; j < 10; ++j) w[14 + j] = 0.0f;   // unused
        bias = kmul * (b_ih0[r] + b_hh0[r]);
    } else {
#pragma unroll
        for (int j = 0; j < H; ++j) {
            w[j]      = kmul * W_ih1[r * H + j];
            w[12 + j] = kmul * W_hh1[r * H + j];
        }
        bias = kmul * (b_ih1[r] + b_hh1[r]);
    }

    // ---------------- state ----------------
    float c = 0.0f;
    float hb[H];                                  // own-layer h broadcast
#pragma unroll
    for (int j = 0; j < H; ++j) hb[j] = 0.0f;

    const float* xp = x + (size_t)b * T * 2;
    float2 xc = *(const float2*)xp;

    for (int t = 0; t <= T; ++t) {
        if (!L1w) {
            if (t < T) {
                const int tn = (t < T - 1) ? (t + 1) : t;
                const float2 xn = *(const float2*)(xp + 2 * tn);
                // L0 gate-row dot (14 terms, scalar FMA)
                float a = fmaf(w[0], xc.x, bias);
                a = fmaf(w[1], xc.y, a);
#pragma unroll
                for (int j = 0; j < H; ++j) a = fmaf(w[2 + j], hb[j], a);
                const float s = fmaf(pre, rcp_(1.0f + exp2_(a)), pa);
                const float F = mdpp<BC1>(s);
                const float G = mdpp<BC2>(s);
                const float O = mdpp<BC3>(s);
                c = fmaf(F, c, s * G);            // valid on gate-0 lanes
                const float hv = O * tanh_(c);
                float* buf = eb + (t & 1) * 16;
                if (pub) buf[uc] = hv;            // publish h0(t), parity t&1
#pragma unroll
                for (int j = 0; j < H; ++j) hb[j] = buf[j];   // own readback
                xc = xn;
            }
        } else {
            if (t > 0) {
                const int s0 = t - 1;             // L1 computes step t-1
                const float* h0buf = eb + (s0 & 1) * 16;
                float a = bias;
#pragma unroll
                for (int j = 0; j < H; ++j) a = fmaf(w[12 + j], hb[j], a);
#pragma unroll
                for (int j = 0; j < H; ++j) a = fmaf(w[j], h0buf[j], a);
                const float sg = fmaf(pre, rcp_(1.0f + exp2_(a)), pa);
                const float F = mdpp<BC1>(sg);
                const float G = mdpp<BC2>(sg);
                const float O = mdpp<BC3>(sg);
                c = fmaf(F, c, sg * G);
                const float hv = O * tanh_(c);
                if (pub) eb[32 + uc] = hv;        // publish h1(t-1)
#pragma unroll
                for (int j = 0; j < H; ++j) hb[j] = eb[32 + j];
            }
        }
        __syncthreads();   // orders h0 handoff: L1 reads parity (t-1)&1 next
    }

    // ---------------- final FC (lane 0 of each L1 wave) ----------------
    if (L1w && lane == 0) {
        float r0 = fc_b[0];
        float r1 = fc_b[1];
#pragma unroll
        for (int j = 0; j < H; ++j) {
            r0 = fmaf(fc_W[j],     hb[j], r0);
            r1 = fmaf(fc_W[H + j], hb[j], r1);
        }
        float2 res; res.x = r0; res.y = r1;
        *(float2*)(out + (size_t)b * 2) = res;
    }
}

extern "C" void kernel_launch(void* const* d_in, const int* in_sizes, int n_in,
                              void* d_out, int out_size, void* d_ws, size_t ws_size,
                              hipStream_t stream) {
    const float* x     = (const float*)d_in[0];
    const float* W_ih0 = (const float*)d_in[1];
    const float* W_hh0 = (const float*)d_in[2];
    const float* b_ih0 = (const float*)d_in[3];
    const float* b_hh0 = (const float*)d_in[4];
    const float* W_ih1 = (const float*)d_in[5];
    const float* W_hh1 = (const float*)d_in[6];
    const float* b_ih1 = (const float*)d_in[7];
    const float* b_hh1 = (const float*)d_in[8];
    const float* fc_W  = (const float*)d_in[9];
    const float* fc_b  = (const float*)d_in[10];
    float* out = (float*)d_out;

    // 4096 elements / 4 per block (8 waves: 4 L0 + 4 L1) = 1024 blocks
    // = exactly 4 blocks/CU = 8 waves/SIMD.
    lstm2_fc_kernel<<<1024, 512, 0, stream>>>(
        x, W_ih0, W_hh0, b_ih0, b_hh0,
        W_ih1, W_hh1, b_ih1, b_hh1, fc_W, fc_b, out);
}

// Round 14
// 283.049 us; speedup vs baseline: 1.0562x; 1.0562x over previous
//
#include <hip/hip_runtime.h>

// LSTMModel: B=4096, T=512, IN=2, H=12, OUT=2, fp32.
// r14 "dense48": FOUR batch elements per wave64.
//   lane = (e = lane>>4, s = lane&15); lane s owns unit-major gate-rows
//   {s, s+16, s+32}: fixed gate g = s&3, units q, q+4, q+8 (q = s>>2).
// -> dots at 100% lane density: 114 scalar FMA per wave-step for 4 elements
//    (the packing floor), gate activations full-density, quad-DPP gathers
//    still work (unit u's i,f,g,o live in one quad at slot T).
// 1024 waves = 1 wave/SIMD, waves_per_eu(1,1) -> 512-VGPR budget for the
// ~165-reg live set (120 weights). ILP from 3 independent dot chains +
// L1 h1-part issued across the h0 LDS round-trip.

namespace {
constexpr int H = 12;
constexpr int T = 512;
constexpr float LOG2E = 1.4426950408889634f;

__device__ __forceinline__ float exp2_(float x) {
    float r; asm("v_exp_f32 %0, %1" : "=v"(r) : "v"(x)); return r;
}
__device__ __forceinline__ float rcp_(float x) { return __builtin_amdgcn_rcpf(x); }
__device__ __forceinline__ void memfence_() { asm volatile("" ::: "memory"); }

template <int CTRL>
__device__ __forceinline__ float mdpp(float v) {
    return __int_as_float(__builtin_amdgcn_mov_dpp(
        __float_as_int(v), CTRL, 0xF, 0xF, true));
}
constexpr int BC1 = 0x55;  // quad broadcast lane1 -> f
constexpr int BC2 = 0xAA;  // quad broadcast lane2 -> g
constexpr int BC3 = 0xFF;  // quad broadcast lane3 -> o

__device__ __forceinline__ float tanh_(float c) {
    // tanh(c) = 2/(1+2^(-2*log2e*c)) - 1
    return fmaf(2.0f, rcp_(1.0f + exp2_(-2.0f * LOG2E * c)), -1.0f);
}
} // namespace

__global__
__attribute__((amdgpu_flat_work_group_size(256, 256)))
__attribute__((amdgpu_waves_per_eu(1, 1)))
void lstm2_fc_kernel(
    const float* __restrict__ x,      // (4096, 512, 2)
    const float* __restrict__ W_ih0,  // (48, 2)   rows r = g*12+u
    const float* __restrict__ W_hh0,  // (48, 12)
    const float* __restrict__ b_ih0,  // (48)
    const float* __restrict__ b_hh0,  // (48)
    const float* __restrict__ W_ih1,  // (48, 12)
    const float* __restrict__ W_hh1,  // (48, 12)
    const float* __restrict__ b_ih1,  // (48)
    const float* __restrict__ b_hh1,  // (48)
    const float* __restrict__ fc_W,   // (2, 12)
    const float* __restrict__ fc_b,   // (2)
    float* __restrict__ out)          // (4096, 2)
{
    const int lane = threadIdx.x & 63;
    const int wid  = __builtin_amdgcn_readfirstlane((int)threadIdx.x >> 6);
    const int e    = lane >> 4;                  // element within wave (0..3)
    const int s    = lane & 15;                  // row-slot within element
    const int g    = s & 3;                      // gate 0:i 1:f 2:g 3:o
    const int q    = s >> 2;                     // unit base (0..3)
    const int b    = blockIdx.x * 16 + wid * 4 + e;

    const float pre  = (g == 2) ? 2.0f : 1.0f;   // tanh via 2*sigm(2x)-1
    const float kmul = -LOG2E * pre;             // exp2 prescale, folded in
    const float pa   = 1.0f - pre;

    // ---- LDS: per-element h rows (h0: [0..191], h1: [192..383]) ----
    __shared__ __align__(16) float sm[384];
    float* h0row = &sm[(wid * 4 + e) * 12];
    float* h1row = &sm[192 + (wid * 4 + e) * 12];
    const bool pub = (g == 0);                   // 16 writer lanes/wave

    // ---- weights: lane covers units u = q+4T, mem row r = g*12+u ----
    float wx0[3], wx1[3], bias0[3], bias1[3];
    float whh0[3][H], wih1[3][H], whh1[3][H];
#pragma unroll
    for (int Tt = 0; Tt < 3; ++Tt) {
        const int r = g * H + (q + 4 * Tt);
        wx0[Tt]   = kmul * W_ih0[r * 2 + 0];
        wx1[Tt]   = kmul * W_ih0[r * 2 + 1];
        bias0[Tt] = kmul * (b_ih0[r] + b_hh0[r]);
        bias1[Tt] = kmul * (b_ih1[r] + b_hh1[r]);
#pragma unroll
        for (int j = 0; j < H; ++j) {
            whh0[Tt][j] = kmul * W_hh0[r * H + j];
            wih1[Tt][j] = kmul * W_ih1[r * H + j];
            whh1[Tt][j] = kmul * W_hh1[r * H + j];
        }
    }

    // ---- state ----
    float c0[3] = {0.0f, 0.0f, 0.0f};
    float c1[3] = {0.0f, 0.0f, 0.0f};
    float h0b[H], h1b[H];
#pragma unroll
    for (int j = 0; j < H; ++j) { h0b[j] = 0.0f; h1b[j] = 0.0f; }

    const float* xp = x + (size_t)b * T * 2;     // same for all 16 lanes of e
    float2 xc = *(const float2*)xp;

    for (int t = 0; t < T; ++t) {
        const int tn = (t < T - 1) ? (t + 1) : t;
        const float2 xn = *(const float2*)(xp + 2 * tn);   // prefetch

        // ---- L0 dots: 3 independent chains x 14 FMA (full lane density) ----
        float a0[3];
#pragma unroll
        for (int Tt = 0; Tt < 3; ++Tt) {
            float acc = fmaf(wx0[Tt], xc.x, bias0[Tt]);
            acc = fmaf(wx1[Tt], xc.y, acc);
#pragma unroll
            for (int j = 0; j < H; ++j) acc = fmaf(whh0[Tt][j], h0b[j], acc);
            a0[Tt] = acc;
        }
        // ---- L0 activations + quad gather + c/h update ----
        float h0v[3];
#pragma unroll
        for (int Tt = 0; Tt < 3; ++Tt) {
            const float sv = fmaf(pre, rcp_(1.0f + exp2_(a0[Tt])), pa);
            const float Fv = mdpp<BC1>(sv);
            const float Gv = mdpp<BC2>(sv);
            const float Ov = mdpp<BC3>(sv);
            c0[Tt] = fmaf(Fv, c0[Tt], sv * Gv);  // valid on g==0 lanes
            h0v[Tt] = Ov * tanh_(c0[Tt]);
        }
        if (pub) {                                // units q, q+4, q+8
            h0row[q + 0] = h0v[0];
            h0row[q + 4] = h0v[1];
            h0row[q + 8] = h0v[2];
        }
        // ---- L1 h1-part issues while the h0 write/readback lands ----
        float a1[3];
#pragma unroll
        for (int Tt = 0; Tt < 3; ++Tt) {
            float acc = bias1[Tt];
#pragma unroll
            for (int j = 0; j < H; ++j) acc = fmaf(whh1[Tt][j], h1b[j], acc);
            a1[Tt] = acc;
        }
        memfence_();
        {   // broadcast readback of h0(t) (same-addr within 16-lane group)
            const float4 r0 = *(const float4*)(h0row + 0);
            const float4 r1 = *(const float4*)(h0row + 4);
            const float4 r2 = *(const float4*)(h0row + 8);
            h0b[0] = r0.x; h0b[1] = r0.y; h0b[2]  = r0.z; h0b[3]  = r0.w;
            h0b[4] = r1.x; h0b[5] = r1.y; h0b[6]  = r1.z; h0b[7]  = r1.w;
            h0b[8] = r2.x; h0b[9] = r2.y; h0b[10] = r2.z; h0b[11] = r2.w;
        }
#pragma unroll
        for (int Tt = 0; Tt < 3; ++Tt) {
            float acc = a1[Tt];
#pragma unroll
            for (int j = 0; j < H; ++j) acc = fmaf(wih1[Tt][j], h0b[j], acc);
            a1[Tt] = acc;
        }
        // ---- L1 activations + update ----
        float h1v[3];
#pragma unroll
        for (int Tt = 0; Tt < 3; ++Tt) {
            const float sv = fmaf(pre, rcp_(1.0f + exp2_(a1[Tt])), pa);
            const float Fv = mdpp<BC1>(sv);
            const float Gv = mdpp<BC2>(sv);
            const float Ov = mdpp<BC3>(sv);
            c1[Tt] = fmaf(Fv, c1[Tt], sv * Gv);
            h1v[Tt] = Ov * tanh_(c1[Tt]);
        }
        if (pub) {
            h1row[q + 0] = h1v[0];
            h1row[q + 4] = h1v[1];
            h1row[q + 8] = h1v[2];
        }
        memfence_();
        {   // readback h1(t) for next step
            const float4 r0 = *(const float4*)(h1row + 0);
            const float4 r1 = *(const float4*)(h1row + 4);
            const float4 r2 = *(const float4*)(h1row + 8);
            h1b[0] = r0.x; h1b[1] = r0.y; h1b[2]  = r0.z; h1b[3]  = r0.w;
            h1b[4] = r1.x; h1b[5] = r1.y; h1b[6]  = r1.z; h1b[7]  = r1.w;
            h1b[8] = r2.x; h1b[9] = r2.y; h1b[10] = r2.z; h1b[11] = r2.w;
        }
        xc = xn;
    }

    // ---- final FC: one lane per element (s == 0); h1b holds h1(T-1) ----
    if (s == 0) {
        float r0 = fc_b[0];
        float r1 = fc_b[1];
#pragma unroll
        for (int j = 0; j < H; ++j) {
            r0 = fmaf(fc_W[j],     h1b[j], r0);
            r1 = fmaf(fc_W[H + j], h1b[j], r1);
        }
        float2 res; res.x = r0; res.y = r1;
        *(float2*)(out + (size_t)b * 2) = res;
    }
}

extern "C" void kernel_launch(void* const* d_in, const int* in_sizes, int n_in,
                              void* d_out, int out_size, void* d_ws, size_t ws_size,
                              hipStream_t stream) {
    const float* x     = (const float*)d_in[0];
    const float* W_ih0 = (const float*)d_in[1];
    const float* W_hh0 = (const float*)d_in[2];
    const float* b_ih0 = (const float*)d_in[3];
    const float* b_hh0 = (const float*)d_in[4];
    const float* W_ih1 = (const float*)d_in[5];
    const float* W_hh1 = (const float*)d_in[6];
    const float* b_ih1 = (const float*)d_in[7];
    const float* b_hh1 = (const float*)d_in[8];
    const float* fc_W  = (const float*)d_in[9];
    const float* fc_b  = (const float*)d_in[10];
    float* out = (float*)d_out;

    // 4096 elements / 16 per block (4 waves x 4 elems) = 256 blocks
    // = 1 block/CU = 1 wave/SIMD.
    lstm2_fc_kernel<<<256, 256, 0, stream>>>(
        x, W_ih0, W_hh0, b_ih0, b_hh0,
        W_ih1, W_hh1, b_ih1, b_hh1, fc_W, fc_b, out);
}

// Round 15
// 268.757 us; speedup vs baseline: 1.1124x; 1.0532x over previous
//
#include <hip/hip_runtime.h>

// LSTMModel: B=4096, T=512, IN=2, H=12, OUT=2, fp32.
// r15 = r13's layer-split pipeline x r14's dense48 lane layout.
// Block = 512 thr = 8 waves: waves 0-3 L0 for 16 elems, waves 4-7 L1 (lagged
// one step, parity double-buffered h0 handoff, one __syncthreads/interval).
// Per wave: 4 elems, lane = (e=lane>>4, s=lane&15), lane owns gate-rows
// g = s&3 of units q, q+4, q+8 (q = s>>2) -> 48 rows, zero idle lanes.
// 2048 waves = 2/SIMD; HW round-robin gives each SIMD one L0 + one L1 wave
// (different mixes -> good interleave). L1 never feeds back to L0.
// 256 blocks = 1 block/CU.

namespace {
constexpr int H = 12;
constexpr int T = 512;
constexpr float LOG2E = 1.4426950408889634f;

__device__ __forceinline__ float exp2_(float x) {
    float r; asm("v_exp_f32 %0, %1" : "=v"(r) : "v"(x)); return r;
}
__device__ __forceinline__ float rcp_(float x) { return __builtin_amdgcn_rcpf(x); }
__device__ __forceinline__ void memfence_() { asm volatile("" ::: "memory"); }

template <int CTRL>
__device__ __forceinline__ float mdpp(float v) {
    return __int_as_float(__builtin_amdgcn_mov_dpp(
        __float_as_int(v), CTRL, 0xF, 0xF, true));
}
constexpr int BC1 = 0x55;  // quad broadcast lane1 -> f
constexpr int BC2 = 0xAA;  // quad broadcast lane2 -> g
constexpr int BC3 = 0xFF;  // quad broadcast lane3 -> o

__device__ __forceinline__ float tanh_(float c) {
    // tanh(c) = 2/(1+2^(-2*log2e*c)) - 1
    return fmaf(2.0f, rcp_(1.0f + exp2_(-2.0f * LOG2E * c)), -1.0f);
}
} // namespace

__global__ __launch_bounds__(512, 2) void lstm2_fc_kernel(
    const float* __restrict__ x,      // (4096, 512, 2)
    const float* __restrict__ W_ih0,  // (48, 2)   rows r = g*12+u
    const float* __restrict__ W_hh0,  // (48, 12)
    const float* __restrict__ b_ih0,  // (48)
    const float* __restrict__ b_hh0,  // (48)
    const float* __restrict__ W_ih1,  // (48, 12)
    const float* __restrict__ W_hh1,  // (48, 12)
    const float* __restrict__ b_ih1,  // (48)
    const float* __restrict__ b_hh1,  // (48)
    const float* __restrict__ fc_W,   // (2, 12)
    const float* __restrict__ fc_b,   // (2)
    float* __restrict__ out)          // (4096, 2)
{
    const int tid  = threadIdx.x;
    const int lane = tid & 63;
    const int wv   = __builtin_amdgcn_readfirstlane(tid >> 6);  // 0..7
    const bool L1w = (wv >= 4);                  // waves 4-7: layer 1
    const int eg   = wv & 3;                     // element-group in block
    const int e    = lane >> 4;                  // elem within wave (0..3)
    const int s    = lane & 15;                  // row-slot
    const int g    = s & 3;                      // gate 0:i 1:f 2:g 3:o
    const int q    = s >> 2;                     // unit base (0..3)
    const int el   = eg * 4 + e;                 // element in block (0..15)
    const int b    = blockIdx.x * 16 + el;

    const float pre  = (g == 2) ? 2.0f : 1.0f;   // tanh via 2*sigm(2x)-1
    const float kmul = -LOG2E * pre;             // exp2 prescale, folded in
    const float pa   = 1.0f - pre;

    // ---- LDS per element (stride 48 floats): h0 parity [0..15],[16..31];
    //      h1 at [32..43]. Element bank bases alternate 0/16 -> 2-way (free).
    __shared__ float sm[16 * 48];
    float* eb = &sm[el * 48];
    const bool pub = (g == 0);                   // 16 writer lanes per wave

    // ---- weights (dense48: units q, q+4, q+8 of fixed gate g) ----
    float wx0c[3], wx1c[3], bias[3];
    float wA[3][H], wB[3][H];   // L0: wA=whh0, wB unused; L1: wA=wih1, wB=whh1
    if (!L1w) {
#pragma unroll
        for (int Tt = 0; Tt < 3; ++Tt) {
            const int r = g * H + (q + 4 * Tt);
            wx0c[Tt] = kmul * W_ih0[r * 2 + 0];
            wx1c[Tt] = kmul * W_ih0[r * 2 + 1];
            bias[Tt] = kmul * (b_ih0[r] + b_hh0[r]);
#pragma unroll
            for (int j = 0; j < H; ++j) {
                wA[Tt][j] = kmul * W_hh0[r * H + j];
                wB[Tt][j] = 0.0f;
            }
        }
    } else {
#pragma unroll
        for (int Tt = 0; Tt < 3; ++Tt) {
            const int r = g * H + (q + 4 * Tt);
            wx0c[Tt] = 0.0f; wx1c[Tt] = 0.0f;
            bias[Tt] = kmul * (b_ih1[r] + b_hh1[r]);
#pragma unroll
            for (int j = 0; j < H; ++j) {
                wA[Tt][j] = kmul * W_ih1[r * H + j];
                wB[Tt][j] = kmul * W_hh1[r * H + j];
            }
        }
    }

    // ---- state ----
    float c[3] = {0.0f, 0.0f, 0.0f};
    float hb[H];                                  // own-layer h broadcast
#pragma unroll
    for (int j = 0; j < H; ++j) hb[j] = 0.0f;

    const float* xp = x + (size_t)b * T * 2;
    float2 xc; xc.x = 0.0f; xc.y = 0.0f;
    if (!L1w) xc = *(const float2*)xp;

    for (int t = 0; t <= T; ++t) {
        if (!L1w) {
            if (t < T) {
                const int tn = (t < T - 1) ? (t + 1) : t;
                const float2 xn = *(const float2*)(xp + 2 * tn);
                // L0 dots: 3 chains x 14 FMA, full lane density
                float a[3];
#pragma unroll
                for (int Tt = 0; Tt < 3; ++Tt) {
                    float acc = fmaf(wx0c[Tt], xc.x, bias[Tt]);
                    acc = fmaf(wx1c[Tt], xc.y, acc);
#pragma unroll
                    for (int j = 0; j < H; ++j) acc = fmaf(wA[Tt][j], hb[j], acc);
                    a[Tt] = acc;
                }
                float hv[3];
#pragma unroll
                for (int Tt = 0; Tt < 3; ++Tt) {
                    const float sv = fmaf(pre, rcp_(1.0f + exp2_(a[Tt])), pa);
                    const float Fv = mdpp<BC1>(sv);
                    const float Gv = mdpp<BC2>(sv);
                    const float Ov = mdpp<BC3>(sv);
                    c[Tt] = fmaf(Fv, c[Tt], sv * Gv);   // valid on g==0 lanes
                    hv[Tt] = Ov * tanh_(c[Tt]);
                }
                float* buf = eb + (t & 1) * 16;          // parity buffer
                if (pub) { buf[q] = hv[0]; buf[q + 4] = hv[1]; buf[q + 8] = hv[2]; }
                memfence_();
                {   // own readback of h0(t) for next step's dot
                    const float4 r0 = *(const float4*)(buf + 0);
                    const float4 r1 = *(const float4*)(buf + 4);
                    const float4 r2 = *(const float4*)(buf + 8);
                    hb[0] = r0.x; hb[1] = r0.y; hb[2]  = r0.z; hb[3]  = r0.w;
                    hb[4] = r1.x; hb[5] = r1.y; hb[6]  = r1.z; hb[7]  = r1.w;
                    hb[8] = r2.x; hb[9] = r2.y; hb[10] = r2.z; hb[11] = r2.w;
                }
                xc = xn;
            }
        } else {
            if (t > 0) {
                // L1 computes step t-1: h0(t-1) from parity buffer (t-1)&1
                const float* h0buf = eb + ((t - 1) & 1) * 16;
                float h0v_[H];
                {
                    const float4 r0 = *(const float4*)(h0buf + 0);
                    const float4 r1 = *(const float4*)(h0buf + 4);
                    const float4 r2 = *(const float4*)(h0buf + 8);
                    h0v_[0] = r0.x; h0v_[1] = r0.y; h0v_[2]  = r0.z; h0v_[3]  = r0.w;
                    h0v_[4] = r1.x; h0v_[5] = r1.y; h0v_[6]  = r1.z; h0v_[7]  = r1.w;
                    h0v_[8] = r2.x; h0v_[9] = r2.y; h0v_[10] = r2.z; h0v_[11] = r2.w;
                }
                float a[3];
#pragma unroll
                for (int Tt = 0; Tt < 3; ++Tt) {
                    float acc = bias[Tt];
#pragma unroll
                    for (int j = 0; j < H; ++j) acc = fmaf(wB[Tt][j], hb[j], acc);
#pragma unroll
                    for (int j = 0; j < H; ++j) acc = fmaf(wA[Tt][j], h0v_[j], acc);
                    a[Tt] = acc;
                }
                float hv[3];
#pragma unroll
                for (int Tt = 0; Tt < 3; ++Tt) {
                    const float sv = fmaf(pre, rcp_(1.0f + exp2_(a[Tt])), pa);
                    const float Fv = mdpp<BC1>(sv);
                    const float Gv = mdpp<BC2>(sv);
                    const float Ov = mdpp<BC3>(sv);
                    c[Tt] = fmaf(Fv, c[Tt], sv * Gv);
                    hv[Tt] = Ov * tanh_(c[Tt]);
                }
                if (pub) { eb[32 + q] = hv[0]; eb[36 + q] = hv[1]; eb[40 + q] = hv[2]; }
                memfence_();
                {   // readback h1(t-1) for next step
                    const float4 r0 = *(const float4*)(eb + 32);
                    const float4 r1 = *(const float4*)(eb + 36);
                    const float4 r2 = *(const float4*)(eb + 40);
                    hb[0] = r0.x; hb[1] = r0.y; hb[2]  = r0.z; hb[3]  = r0.w;
                    hb[4] = r1.x; hb[5] = r1.y; hb[6]  = r1.z; hb[7]  = r1.w;
                    hb[8] = r2.x; hb[9] = r2.y; hb[10] = r2.z; hb[11] = r2.w;
                }
            }
        }
        __syncthreads();   // h0 handoff order: L1 reads parity (t)&1 next interval
    }

    // ---- final FC: L1 waves, one lane per element (s==0); hb = h1(T-1) ----
    if (L1w && s == 0) {
        float r0 = fc_b[0];
        float r1 = fc_b[1];
#pragma unroll
        for (int j = 0; j < H; ++j) {
            r0 = fmaf(fc_W[j],     hb[j], r0);
            r1 = fmaf(fc_W[H + j], hb[j], r1);
        }
        float2 res; res.x = r0; res.y = r1;
        *(float2*)(out + (size_t)b * 2) = res;
    }
}

extern "C" void kernel_launch(void* const* d_in, const int* in_sizes, int n_in,
                              void* d_out, int out_size, void* d_ws, size_t ws_size,
                              hipStream_t stream) {
    const float* x     = (const float*)d_in[0];
    const float* W_ih0 = (const float*)d_in[1];
    const float* W_hh0 = (const float*)d_in[2];
    const float* b_ih0 = (const float*)d_in[3];
    const float* b_hh0 = (const float*)d_in[4];
    const float* W_ih1 = (const float*)d_in[5];
    const float* W_hh1 = (const float*)d_in[6];
    const float* b_ih1 = (const float*)d_in[7];
    const float* b_hh1 = (const float*)d_in[8];
    const float* fc_W  = (const float*)d_in[9];
    const float* fc_b  = (const float*)d_in[10];
    float* out = (float*)d_out;

    // 4096 elems / 16 per block (8 waves: 4 L0-dense48 + 4 L1-dense48)
    // = 256 blocks = 1 block/CU = 2 waves/SIMD (one L0 + one L1 per SIMD).
    lstm2_fc_kernel<<<256, 512, 0, stream>>>(
        x, W_ih0, W_hh0, b_ih0, b_hh0,
        W_ih1, W_hh1, b_ih1, b_hh1, fc_W, fc_b, out);
}